// Round 5
// baseline (140.413 us; speedup 1.0000x reference)
//
#include <hip/hip_runtime.h>

// NetVLAD: N=16, C=1024, P=1024, K=32. Four plain dispatches (cooperative
// launch abandoned: it never executed under graph capture -> zero output).
//  k_logits: (n, 128c-slab s<8, 256p-quarter) — read x ONCE, linearly (1KB
//     contiguous segments). MFMA unnormalized logit partials (rnorm factors
//     out of softmax arg) + ssq partials. 4x4 register transpose into
//     XOR-swizzled LDS; W staged bf16 in LDS (136-row = 272B, 16B-aligned).
//  k_soft: (n, 32p) — reduce partials, rnorm, softmax over k, attn bf16,
//     asum partials. Fully parallel (no serial t<32 softmax loop).
//  k_vlad: (n, 32c-tile) — vlad MFMA fragment-direct from global: attn
//     (L2-hot) x x*rnorm (x L3-resident). Fused -asum*cent, ssq partials.
//     (Round-3-verified code.)
//  k_out: (n, k) — intra + global norms, scaled output write. 512 blocks.
// Runtime dtype detect (fp32 vs bf16) in k_logits; fp32 accumulate throughout.
#define NB   16
#define CC   1024
#define PP   1024
#define KK   32
#define EPSF 1e-12f
#define NSLAB 8      // c-slabs of 128

typedef __attribute__((ext_vector_type(8))) short  bf16x8;
typedef __attribute__((ext_vector_type(4))) float  f32x4;

__device__ __forceinline__ float bf2f(unsigned short u) {
    union { unsigned int i; float f; } v; v.i = ((unsigned int)u) << 16; return v.f;
}
__device__ __forceinline__ unsigned short f2bf(float f) {
    union { float f; unsigned int i; } v; v.f = f;
    return (unsigned short)((v.i + 0x7fffu + ((v.i >> 16) & 1u)) >> 16);  // RNE
}

template <typename T> struct IO;
template <> struct IO<float> {
    static __device__ __forceinline__ float ld(const float* p) { return *p; }
    static __device__ __forceinline__ f32x4 ld4(const float* p) { return *(const f32x4*)p; }
    static __device__ __forceinline__ void st4(float* p, f32x4 v) { *(f32x4*)p = v; }
};
template <> struct IO<unsigned short> {
    static __device__ __forceinline__ float ld(const unsigned short* p) { return bf2f(*p); }
    static __device__ __forceinline__ f32x4 ld4(const unsigned short* p) {
        const ushort4 u = *(const ushort4*)p;
        f32x4 r; r[0] = bf2f(u.x); r[1] = bf2f(u.y); r[2] = bf2f(u.z); r[3] = bf2f(u.w);
        return r;
    }
    static __device__ __forceinline__ void st4(unsigned short* p, f32x4 v) {
        ushort4 u;
        u.x = f2bf(v[0]); u.y = f2bf(v[1]); u.z = f2bf(v[2]); u.w = f2bf(v[3]);
        *(ushort4*)p = u;
    }
};

// ---------------------------------------------------------------------------
// K1: logits partials. grid 512 = (n, s, pq), block 256.
// ---------------------------------------------------------------------------
struct LogSmem {
    unsigned short xT[256][72];   // [p][c] 144B rows (16B-aligned), XOR-swz cols
    unsigned short W[32][136];    // [k][c] 272B rows (16B-aligned)
    float red[8][256];            // ssq reduce [rowgroup][p]
};

template <typename T>
__device__ __forceinline__ void logits_body(const T* __restrict__ x,
                                            const T* __restrict__ w,
                                            LogSmem& sm,
                                            float* __restrict__ logits_p,
                                            float* __restrict__ ssq_p) {
    const int b = blockIdx.x, t = threadIdx.x;
    const int n = b >> 5, r = b & 31, s = r >> 2, pq = r & 3;
    const int c0 = s * 128, p0 = pq * 256;
    const int lane = t & 63, wvi = t >> 6;
    const int quad = lane >> 4, l15 = lane & 15;
    // stage W[32][c0:c0+128] bf16 (each thread: one k-row chunk of 16 c)
    {
        const int k = t >> 3, coff = (t & 7) * 16;
        #pragma unroll
        for (int j = 0; j < 4; ++j) {
            const f32x4 v = IO<T>::ld4(&w[k * CC + c0 + coff + 4 * j]);
            ushort4 u;
            u.x = f2bf(v[0]); u.y = f2bf(v[1]); u.z = f2bf(v[2]); u.w = f2bf(v[3]);
            *(ushort4*)&sm.W[k][coff + 4 * j] = u;
        }
    }
    const int g  = t >> 5;          // rowgroup 0..7 (4 c-rows each)
    const int po = (t & 31) * 8;    // p-octet base 0..248
    const size_t xb = (size_t)n * CC * PP;
    float ssq_t[8] = {};
    f32x4 acc[2][4] = {};

    #pragma unroll
    for (int ch = 0; ch < 4; ++ch) {
        // load 4 c-rows x 8 p (1KB contiguous per row across 32 lanes)
        f32x4 vr[4][2];
        #pragma unroll
        for (int i = 0; i < 4; ++i) {
            const size_t row = xb + (size_t)(c0 + ch * 32 + g * 4 + i) * PP + p0 + po;
            vr[i][0] = IO<T>::ld4(&x[row]);
            vr[i][1] = IO<T>::ld4(&x[row + 4]);
        }
        __syncthreads();   // prev chunk's MFMA reads done (covers W stage on ch0)
        // 4x4 register transpose -> swizzled LDS, + sumsq
        #pragma unroll
        for (int hj = 0; hj < 8; ++hj) {
            const int h = hj >> 2, j = hj & 3;
            ssq_t[hj] += vr[0][h][j] * vr[0][h][j] + vr[1][h][j] * vr[1][h][j]
                       + vr[2][h][j] * vr[2][h][j] + vr[3][h][j] * vr[3][h][j];
            ushort4 u;
            u.x = f2bf(vr[0][h][j]); u.y = f2bf(vr[1][h][j]);
            u.z = f2bf(vr[2][h][j]); u.w = f2bf(vr[3][h][j]);
            const int p_loc = po + hj;
            const int swz = ((p_loc >> 3) ^ (p_loc >> 5)) & 3;
            const int colg = (((g >> 1) ^ swz) * 8) + (g & 1) * 4;   // ushorts
            *(ushort4*)&sm.xT[p_loc][colg] = u;
        }
        __syncthreads();
        // MFMA: wave owns 64-p window; A = W k-rows, B = xT p-rows
        #pragma unroll
        for (int mt = 0; mt < 2; ++mt) {
            const bf16x8 av = *(const bf16x8*)&sm.W[mt * 16 + l15][ch * 32 + quad * 8];
            #pragma unroll
            for (int pt = 0; pt < 4; ++pt) {
                const int p_loc = wvi * 64 + pt * 16 + l15;
                const int swz = ((p_loc >> 3) ^ (p_loc >> 5)) & 3;
                const bf16x8 bv = *(const bf16x8*)&sm.xT[p_loc][(quad ^ swz) * 8];
                acc[mt][pt] = __builtin_amdgcn_mfma_f32_16x16x32_bf16(av, bv, acc[mt][pt], 0, 0, 0);
            }
        }
    }
    // write logit partials: D row = k (quad*4+reg), col = p (l15)
    #pragma unroll
    for (int mt = 0; mt < 2; ++mt)
        #pragma unroll
        for (int pt = 0; pt < 4; ++pt)
            #pragma unroll
            for (int reg = 0; reg < 4; ++reg) {
                const int kk = mt * 16 + quad * 4 + reg;
                const int p  = p0 + wvi * 64 + pt * 16 + l15;
                logits_p[(((size_t)s * NB + n) * KK + kk) * PP + p] = acc[mt][pt][reg];
            }
    // ssq partial: reduce over 8 rowgroups via LDS
    #pragma unroll
    for (int hj = 0; hj < 8; ++hj) sm.red[g][po + hj] = ssq_t[hj];
    __syncthreads();
    {
        float ss = 0.f;
        #pragma unroll
        for (int gg = 0; gg < 8; ++gg) ss += sm.red[gg][t];
        ssq_p[((size_t)s * NB + n) * PP + p0 + t] = ss;
    }
}

__global__ __launch_bounds__(256) void k_logits(const void* __restrict__ xv,
                                                const void* __restrict__ wv,
                                                int* __restrict__ flag,
                                                float* __restrict__ logits_p,
                                                float* __restrict__ ssq_p) {
    __shared__ LogSmem sm;
    __shared__ int s_bad;
    const int t = threadIdx.x;
    if (t == 0) s_bad = 0;
    __syncthreads();
    {   // per-block dtype detect (8KB prefix, L2-broadcast across blocks)
        const unsigned short* xu = (const unsigned short*)xv;
        int bad = 0;
        for (int i = t; i < 4096; i += 256)
            if (((xu[i] >> 7) & 0xFFu) > 0x9Fu) bad = 1;
        if (bad) atomicOr(&s_bad, 1);
    }
    __syncthreads();
    const int f = s_bad;
    if (blockIdx.x == 0 && t == 0) flag[0] = f;   // for later kernels
    if (f) logits_body<float>((const float*)xv, (const float*)wv, sm, logits_p, ssq_p);
    else   logits_body<unsigned short>((const unsigned short*)xv, (const unsigned short*)wv,
                                       sm, logits_p, ssq_p);
}

// ---------------------------------------------------------------------------
// K2: softmax. grid 512 = (n, 32p), block 256. Dtype-independent.
// ---------------------------------------------------------------------------
__global__ __launch_bounds__(256) void k_soft(const float* __restrict__ logits_p,
                                              const float* __restrict__ ssq_p,
                                              float* __restrict__ rnorm_ws,
                                              unsigned short* __restrict__ attn_g,
                                              float* __restrict__ asum_p) {
    __shared__ float s_rn[32];
    __shared__ float s_as[32];
    const int b = blockIdx.x, t = threadIdx.x;
    const int n = b >> 5, ps = b & 31;
    const int p0 = ps * 32;
    if (t < 32) {
        float ss = 0.f;
        #pragma unroll
        for (int s = 0; s < NSLAB; ++s) ss += ssq_p[((size_t)s * NB + n) * PP + p0 + t];
        const float rr = 1.0f / fmaxf(sqrtf(ss), EPSF);
        s_rn[t] = rr;
        rnorm_ws[n * PP + p0 + t] = rr;
        s_as[t] = 0.f;
    }
    __syncthreads();
    const int pl = t >> 3, kg = (t & 7) * 4;
    const float rn = s_rn[pl];
    float l[4];
    #pragma unroll
    for (int j = 0; j < 4; ++j) {
        float a = 0.f;
        #pragma unroll
        for (int s = 0; s < NSLAB; ++s)
            a += logits_p[(((size_t)s * NB + n) * KK + kg + j) * PP + p0 + pl];
        l[j] = a * rn;
    }
    float mx = fmaxf(fmaxf(l[0], l[1]), fmaxf(l[2], l[3]));
    mx = fmaxf(mx, __shfl_xor(mx, 1, 64));
    mx = fmaxf(mx, __shfl_xor(mx, 2, 64));
    mx = fmaxf(mx, __shfl_xor(mx, 4, 64));
    float e[4], sum = 0.f;
    #pragma unroll
    for (int j = 0; j < 4; ++j) { e[j] = expf(l[j] - mx); sum += e[j]; }
    sum += __shfl_xor(sum, 1, 64);
    sum += __shfl_xor(sum, 2, 64);
    sum += __shfl_xor(sum, 4, 64);
    const float inv = 1.0f / sum;
    #pragma unroll
    for (int j = 0; j < 4; ++j) {
        const unsigned short uu = f2bf(e[j] * inv);
        attn_g[((size_t)n * KK + kg + j) * PP + p0 + pl] = uu;
        atomicAdd(&s_as[kg + j], bf2f(uu));
    }
    __syncthreads();
    if (t < 32) asum_p[(n * 32 + ps) * KK + t] = s_as[t];
}

// ---------------------------------------------------------------------------
// K3: vlad GEMM, fragment-direct from global (round-3-verified).
// grid 512 = (n, 32c-tile), block 256.
// ---------------------------------------------------------------------------
struct VladSmem { float asum[32]; float ssq[32]; };

template <typename T>
__device__ __forceinline__ void vlad_body(const T* __restrict__ x,
                                          const T* __restrict__ cent, VladSmem& sm,
                                          const float* __restrict__ rnorm_ws,
                                          const unsigned short* __restrict__ attn_g,
                                          const float* __restrict__ asum_p,
                                          float* __restrict__ vlad,
                                          float* __restrict__ ssqnk_p) {
    const int b = blockIdx.x, t = threadIdx.x;
    const int n = b >> 5, ct = b & 31;
    const int lane = t & 63, wvi = t >> 6;
    const int quad = lane >> 4, l15 = lane & 15;
    const int mt = wvi & 1, nt = wvi >> 1;
    const int krow = mt * 16 + l15;
    const int crow = ct * 32 + nt * 16 + l15;
    if (t < 32) {
        float s = 0.f;
        #pragma unroll
        for (int ps = 0; ps < 32; ++ps) s += asum_p[(n * 32 + ps) * KK + t];
        sm.asum[t] = s;
        sm.ssq[t] = 0.f;
    }
    __syncthreads();
    const unsigned short* apq = attn_g + ((size_t)n * KK + krow) * PP + quad * 8;
    const T* xp = x + (size_t)n * CC * PP + (size_t)crow * PP + quad * 8;
    const float* rp = rnorm_ws + n * PP + quad * 8;
    f32x4 acc = {0.f, 0.f, 0.f, 0.f};
    // depth-4 register pipeline over 32 p-steps (full unroll -> static slots)
    bf16x8 avq[4]; f32x4 xq0[4], xq1[4], rq0[4], rq1[4];
    #pragma unroll
    for (int i = 0; i < 4; ++i) {
        const int o = i * 32;
        avq[i] = *(const bf16x8*)&apq[o];
        xq0[i] = IO<T>::ld4(&xp[o]); xq1[i] = IO<T>::ld4(&xp[o + 4]);
        rq0[i] = *(const f32x4*)&rp[o]; rq1[i] = *(const f32x4*)&rp[o + 4];
    }
    #pragma unroll
    for (int st = 0; st < 32; ++st) {
        const int sl = st & 3;
        bf16x8 bv;
        #pragma unroll
        for (int j = 0; j < 4; ++j) {
            bv[j]     = (short)f2bf(xq0[sl][j] * rq0[sl][j]);
            bv[4 + j] = (short)f2bf(xq1[sl][j] * rq1[sl][j]);
        }
        acc = __builtin_amdgcn_mfma_f32_16x16x32_bf16(avq[sl], bv, acc, 0, 0, 0);
        if (st + 4 < 32) {
            const int o = (st + 4) * 32;
            avq[sl] = *(const bf16x8*)&apq[o];
            xq0[sl] = IO<T>::ld4(&xp[o]); xq1[sl] = IO<T>::ld4(&xp[o + 4]);
            rq0[sl] = *(const f32x4*)&rp[o]; rq1[sl] = *(const f32x4*)&rp[o + 4];
        }
    }
    #pragma unroll
    for (int reg = 0; reg < 4; ++reg) {
        const int kk = mt * 16 + quad * 4 + reg;
        const float A = sm.asum[kk];
        const float v = acc[reg] - A * IO<T>::ld(&cent[kk * CC + crow]);
        vlad[((size_t)n * KK + kk) * CC + crow] = v;
        float sq = v * v;
        sq += __shfl_xor(sq, 1, 64);
        sq += __shfl_xor(sq, 2, 64);
        sq += __shfl_xor(sq, 4, 64);
        sq += __shfl_xor(sq, 8, 64);
        if (l15 == 0) atomicAdd(&sm.ssq[kk], sq);
    }
    __syncthreads();
    if (t < 32) ssqnk_p[(n * 32 + ct) * KK + t] = sm.ssq[t];
}

__global__ __launch_bounds__(256) void k_vlad(const void* __restrict__ xv,
                                              const void* __restrict__ centv,
                                              const int* __restrict__ flag,
                                              const float* __restrict__ rnorm_ws,
                                              const unsigned short* __restrict__ attn_g,
                                              const float* __restrict__ asum_p,
                                              float* __restrict__ vlad,
                                              float* __restrict__ ssqnk_p) {
    __shared__ VladSmem sm;
    if (*flag) vlad_body<float>((const float*)xv, (const float*)centv, sm, rnorm_ws,
                                attn_g, asum_p, vlad, ssqnk_p);
    else       vlad_body<unsigned short>((const unsigned short*)xv, (const unsigned short*)centv,
                                         sm, rnorm_ws, attn_g, asum_p, vlad, ssqnk_p);
}

// ---------------------------------------------------------------------------
// K4: factors + scaled output. grid 512 = (n, k), block 256.
// ---------------------------------------------------------------------------
struct OutSmem { float ssq[32]; float rint[32]; float rg; };

template <typename T>
__device__ __forceinline__ void out_body(const float* __restrict__ vlad,
                                         const float* __restrict__ ssqnk_p,
                                         OutSmem& sm, T* __restrict__ out) {
    const int b = blockIdx.x, t = threadIdx.x;
    const int n = b >> 5, k = b & 31;
    if (t < 32) {
        float s = 0.f;
        #pragma unroll
        for (int ct = 0; ct < 32; ++ct) s += ssqnk_p[(n * 32 + ct) * KK + t];
        sm.ssq[t] = s;
    }
    __syncthreads();
    if (t < 64) {
        const float s = (t < 32) ? sm.ssq[t] : 0.f;
        const float rr = 1.0f / fmaxf(sqrtf(s), EPSF);
        float gg = s * rr * rr;
        #pragma unroll
        for (int off = 32; off > 0; off >>= 1) gg += __shfl_down(gg, off, 64);
        if (t == 0) sm.rg = 1.0f / fmaxf(sqrtf(gg), EPSF);
        if (t < 32) sm.rint[t] = rr;
    }
    __syncthreads();
    const float f = sm.rint[k] * sm.rg;
    const size_t ob = ((size_t)n * KK + k) * CC + 4 * t;
    f32x4 v = *(const f32x4*)&vlad[ob];
    v[0] *= f; v[1] *= f; v[2] *= f; v[3] *= f;
    IO<T>::st4(&out[ob], v);
}

__global__ __launch_bounds__(256) void k_out(const float* __restrict__ vlad,
                                             const float* __restrict__ ssqnk_p,
                                             const int* __restrict__ flag,
                                             void* __restrict__ outv) {
    __shared__ OutSmem sm;
    if (*flag) out_body<float>(vlad, ssqnk_p, sm, (float*)outv);
    else       out_body<unsigned short>(vlad, ssqnk_p, sm, (unsigned short*)outv);
}

extern "C" void kernel_launch(void* const* d_in, const int* in_sizes, int n_in,
                              void* d_out, int out_size, void* d_ws, size_t ws_size,
                              hipStream_t stream) {
    const void* x    = d_in[0];
    const void* w    = d_in[1];
    const void* cent = d_in[2];

    float* ws        = (float*)d_ws;
    float* logits_p  = ws;                                       // 8*16*32*1024 fl (16MB)
    float* ssq_p     = logits_p + (size_t)NSLAB * NB * KK * PP;  // 8*16*1024 fl
    float* rnorm_ws  = ssq_p + (size_t)NSLAB * NB * PP;          // 16384 fl
    float* asum_p    = rnorm_ws + NB * PP;                       // 16*32*32 fl
    float* ssqnk_p   = asum_p + NB * 32 * KK;                    // 16*32*32 fl
    float* vlad      = ssqnk_p + NB * 32 * KK;                   // 16*32*1024 fl (2MB)
    int*   flag      = (int*)(vlad + (size_t)NB * KK * CC);      // 4 ints
    unsigned short* attn_g = (unsigned short*)(flag + 4);        // 16*32*1024 sh (1MB)

    k_logits<<<NB * 32, 256, 0, stream>>>(x, w, flag, logits_p, ssq_p);
    k_soft<<<NB * 32, 256, 0, stream>>>(logits_p, ssq_p, rnorm_ws, attn_g, asum_p);
    k_vlad<<<NB * 32, 256, 0, stream>>>(x, cent, flag, rnorm_ws, attn_g, asum_p,
                                        vlad, ssqnk_p);
    k_out<<<NB * KK, 256, 0, stream>>>(vlad, ssqnk_p, flag, d_out);
}

// Round 8
// 132.965 us; speedup vs baseline: 1.0560x; 1.0560x over previous
//
#include <hip/hip_runtime.h>

// NetVLAD: N=16, C=1024, P=1024, K=32. Three dispatches.
//  k_attn: FUSED logits+rnorm+softmax+attn. grid 256 = (n, 64-p tile),
//     block 256 = 4 waves. K-loop: 16 chunks of 64c; fp32 x loads in 256B
//     contiguous segments, 4x4 register transpose -> dbuf LDS, depth-1
//     register prefetch, one lgkmcnt-only barrier per chunk (global loads
//     stay in flight). MFMA logits (M=32k, N=64p, Kdim=1024c). Epilogue:
//     sumsq->rnorm, in-register softmax (shfl over quads), attn bf16 staged
//     in LDS -> coalesced writes + asum partials. NO logits round-trip.
//  k_vlad: (n, 32c-tile) vlad MFMA fragment-direct from global (attn L2-hot,
//     x L3-resident). Fused -asum*cent, ssq partials. (R5-verified code.)
//  k_out: (n, k) intra+global norms, scaled write. (R5-verified code.)
// Runtime dtype detect (fp32 vs bf16) per block; fp32 accumulate throughout.
// (Rounds 6-7 were container-level infra failures with no kernel execution;
//  identical resubmit to finally obtain the measurement.)
#define NB   16
#define CC   1024
#define PP   1024
#define KK   32
#define EPSF 1e-12f

typedef __attribute__((ext_vector_type(8))) short  bf16x8;
typedef __attribute__((ext_vector_type(4))) float  f32x4;

__device__ __forceinline__ float bf2f(unsigned short u) {
    union { unsigned int i; float f; } v; v.i = ((unsigned int)u) << 16; return v.f;
}
__device__ __forceinline__ unsigned short f2bf(float f) {
    union { float f; unsigned int i; } v; v.f = f;
    return (unsigned short)((v.i + 0x7fffu + ((v.i >> 16) & 1u)) >> 16);  // RNE
}

template <typename T> struct IO;
template <> struct IO<float> {
    static __device__ __forceinline__ float ld(const float* p) { return *p; }
    static __device__ __forceinline__ f32x4 ld4(const float* p) { return *(const f32x4*)p; }
    static __device__ __forceinline__ void st4(float* p, f32x4 v) { *(f32x4*)p = v; }
};
template <> struct IO<unsigned short> {
    static __device__ __forceinline__ float ld(const unsigned short* p) { return bf2f(*p); }
    static __device__ __forceinline__ f32x4 ld4(const unsigned short* p) {
        const ushort4 u = *(const ushort4*)p;
        f32x4 r; r[0] = bf2f(u.x); r[1] = bf2f(u.y); r[2] = bf2f(u.z); r[3] = bf2f(u.w);
        return r;
    }
    static __device__ __forceinline__ void st4(unsigned short* p, f32x4 v) {
        ushort4 u;
        u.x = f2bf(v[0]); u.y = f2bf(v[1]); u.z = f2bf(v[2]); u.w = f2bf(v[3]);
        *(ushort4*)p = u;
    }
};

// Barrier WITHOUT vmcnt drain: waves wait only their LDS ops; prefetch global
// loads stay in flight across the barrier.
__device__ __forceinline__ void wg_sync_fast() {
    asm volatile("s_waitcnt lgkmcnt(0)" ::: "memory");
    __builtin_amdgcn_s_barrier();
    asm volatile("" ::: "memory");
}

// ---------------------------------------------------------------------------
// K1: fused attn. grid 256 = (n<<4 | ptile), block 256.
// ---------------------------------------------------------------------------
struct __align__(16) AttnSmem {
    unsigned short xT[2][64][72];   // [buf][p][c] 144B rows (16B-aligned)
    unsigned short Wl[2][32][72];   // [buf][k][c]; Wl[0] reused for attn stage
    float red[16][64];              // sumsq partials [row-quad][p]
    float rn[64];
};

template <typename T>
__device__ __forceinline__ void attn_body(const T* __restrict__ x,
                                          const T* __restrict__ w,
                                          AttnSmem& sm,
                                          float* __restrict__ rnorm_ws,
                                          unsigned short* __restrict__ attn_g,
                                          float* __restrict__ asum_p) {
    const int b = blockIdx.x, t = threadIdx.x;
    const int n = b >> 4, pt = b & 15, p0 = pt * 64;
    const int lane = t & 63, wv = t >> 6;
    const int quad = lane >> 4, l15 = lane & 15;
    const int i = t >> 4;          // row-quad 0..15 (4 c-rows per chunk)
    const int j = t & 15;          // p-quad 0..15 (4 p)
    const int wk = t >> 3;         // W staging k-row 0..31
    const int wcoff = (t & 7) * 8; // W staging c-offset
    const size_t xb = (size_t)n * CC * PP + p0;

    float ssq_t[4] = {0.f, 0.f, 0.f, 0.f};
    f32x4 acc0 = {0.f, 0.f, 0.f, 0.f}, acc1 = {0.f, 0.f, 0.f, 0.f};

    // depth-1 prefetch registers (chunk ch data)
    f32x4 xr[4]; f32x4 wr[2];
    #pragma unroll
    for (int r = 0; r < 4; ++r)
        xr[r] = IO<T>::ld4(&x[xb + (size_t)(4 * i + r) * PP + 4 * j]);
    wr[0] = IO<T>::ld4(&w[wk * CC + wcoff]);
    wr[1] = IO<T>::ld4(&w[wk * CC + wcoff + 4]);

    #pragma unroll
    for (int ch = 0; ch < 16; ++ch) {
        const int buf = ch & 1;
        // transpose-store x chunk + sumsq
        #pragma unroll
        for (int jj = 0; jj < 4; ++jj) {
            ssq_t[jj] += xr[0][jj] * xr[0][jj] + xr[1][jj] * xr[1][jj]
                       + xr[2][jj] * xr[2][jj] + xr[3][jj] * xr[3][jj];
            ushort4 u;
            u.x = f2bf(xr[0][jj]); u.y = f2bf(xr[1][jj]);
            u.z = f2bf(xr[2][jj]); u.w = f2bf(xr[3][jj]);
            *(ushort4*)&sm.xT[buf][4 * j + jj][4 * i] = u;
        }
        // store W chunk
        {
            ushort4 u0, u1;
            u0.x = f2bf(wr[0][0]); u0.y = f2bf(wr[0][1]);
            u0.z = f2bf(wr[0][2]); u0.w = f2bf(wr[0][3]);
            u1.x = f2bf(wr[1][0]); u1.y = f2bf(wr[1][1]);
            u1.z = f2bf(wr[1][2]); u1.w = f2bf(wr[1][3]);
            *(ushort4*)&sm.Wl[buf][wk][wcoff]     = u0;
            *(ushort4*)&sm.Wl[buf][wk][wcoff + 4] = u1;
        }
        // issue next-chunk loads (stay in flight across the barrier)
        if (ch < 15) {
            const int c0 = (ch + 1) * 64;
            #pragma unroll
            for (int r = 0; r < 4; ++r)
                xr[r] = IO<T>::ld4(&x[xb + (size_t)(c0 + 4 * i + r) * PP + 4 * j]);
            wr[0] = IO<T>::ld4(&w[wk * CC + c0 + wcoff]);
            wr[1] = IO<T>::ld4(&w[wk * CC + c0 + wcoff + 4]);
        }
        wg_sync_fast();
        // MFMA: A = W k-rows, B = xT p-rows; D row=k(quad*4+reg), col=p(l15)
        #pragma unroll
        for (int ks = 0; ks < 2; ++ks) {
            const bf16x8 bv  = *(const bf16x8*)&sm.xT[buf][wv * 16 + l15][ks * 32 + quad * 8];
            const bf16x8 a0  = *(const bf16x8*)&sm.Wl[buf][l15][ks * 32 + quad * 8];
            const bf16x8 a1  = *(const bf16x8*)&sm.Wl[buf][16 + l15][ks * 32 + quad * 8];
            acc0 = __builtin_amdgcn_mfma_f32_16x16x32_bf16(a0, bv, acc0, 0, 0, 0);
            acc1 = __builtin_amdgcn_mfma_f32_16x16x32_bf16(a1, bv, acc1, 0, 0, 0);
        }
        // dbuf: next iter stores to other buffer; one barrier/chunk suffices.
    }
    // sumsq partials -> rnorm
    #pragma unroll
    for (int jj = 0; jj < 4; ++jj) sm.red[i][4 * j + jj] = ssq_t[jj];
    __syncthreads();
    if (t < 64) {
        float ss = 0.f;
        #pragma unroll
        for (int g = 0; g < 16; ++g) ss += sm.red[g][t];
        const float rr = 1.0f / fmaxf(sqrtf(ss), EPSF);
        sm.rn[t] = rr;
        rnorm_ws[n * PP + p0 + t] = rr;
    }
    __syncthreads();
    // in-register softmax: lane holds k = {quad*4+reg, 16+quad*4+reg},
    // p = p0 + wv*16 + l15. Reduce over k via shfl across quads (xor 16, 32).
    {
        const float rr = sm.rn[wv * 16 + l15];
        float l[8];
        #pragma unroll
        for (int reg = 0; reg < 4; ++reg) { l[reg] = acc0[reg] * rr; l[4 + reg] = acc1[reg] * rr; }
        float mx = l[0];
        #pragma unroll
        for (int q = 1; q < 8; ++q) mx = fmaxf(mx, l[q]);
        mx = fmaxf(mx, __shfl_xor(mx, 16, 64));
        mx = fmaxf(mx, __shfl_xor(mx, 32, 64));
        float e[8], sum = 0.f;
        #pragma unroll
        for (int q = 0; q < 8; ++q) { e[q] = expf(l[q] - mx); sum += e[q]; }
        sum += __shfl_xor(sum, 16, 64);
        sum += __shfl_xor(sum, 32, 64);
        const float inv = 1.0f / sum;
        // stage attn bf16 into Wl[0] as [k][p] (main loop done; safe after syncs)
        #pragma unroll
        for (int reg = 0; reg < 4; ++reg) {
            sm.Wl[0][quad * 4 + reg][wv * 16 + l15]      = f2bf(e[reg] * inv);
            sm.Wl[0][16 + quad * 4 + reg][wv * 16 + l15] = f2bf(e[4 + reg] * inv);
        }
    }
    __syncthreads();
    // coalesced attn write (16B/thread) + asum partial
    {
        const int k = t >> 3, po = (t & 7) * 8;
        const ushort4 u0 = *(const ushort4*)&sm.Wl[0][k][po];
        const ushort4 u1 = *(const ushort4*)&sm.Wl[0][k][po + 4];
        *(ushort4*)&attn_g[((size_t)n * KK + k) * PP + p0 + po]     = u0;
        *(ushort4*)&attn_g[((size_t)n * KK + k) * PP + p0 + po + 4] = u1;
        float s = bf2f(u0.x) + bf2f(u0.y) + bf2f(u0.z) + bf2f(u0.w)
                + bf2f(u1.x) + bf2f(u1.y) + bf2f(u1.z) + bf2f(u1.w);
        s += __shfl_xor(s, 1, 64);
        s += __shfl_xor(s, 2, 64);
        s += __shfl_xor(s, 4, 64);
        if ((t & 7) == 0) asum_p[(n * 16 + pt) * KK + k] = s;
    }
}

__global__ __launch_bounds__(256) void k_attn(const void* __restrict__ xv,
                                              const void* __restrict__ wv,
                                              int* __restrict__ flag,
                                              float* __restrict__ rnorm_ws,
                                              unsigned short* __restrict__ attn_g,
                                              float* __restrict__ asum_p) {
    __shared__ AttnSmem sm;
    __shared__ int s_bad;
    const int t = threadIdx.x;
    if (t == 0) s_bad = 0;
    __syncthreads();
    {   // per-block dtype detect (8KB prefix, L2-broadcast across blocks)
        const unsigned short* xu = (const unsigned short*)xv;
        int bad = 0;
        for (int ii = t; ii < 4096; ii += 256)
            if (((xu[ii] >> 7) & 0xFFu) > 0x9Fu) bad = 1;
        if (bad) atomicOr(&s_bad, 1);
    }
    __syncthreads();
    const int f = s_bad;
    if (blockIdx.x == 0 && t == 0) flag[0] = f;   // for later kernels
    if (f) attn_body<float>((const float*)xv, (const float*)wv, sm, rnorm_ws, attn_g, asum_p);
    else   attn_body<unsigned short>((const unsigned short*)xv, (const unsigned short*)wv,
                                     sm, rnorm_ws, attn_g, asum_p);
}

// ---------------------------------------------------------------------------
// K2: vlad GEMM, fragment-direct from global (R5-verified).
// grid 512 = (n, 32c-tile), block 256.
// ---------------------------------------------------------------------------
struct VladSmem { float asum[32]; float ssq[32]; };

template <typename T>
__device__ __forceinline__ void vlad_body(const T* __restrict__ x,
                                          const T* __restrict__ cent, VladSmem& sm,
                                          const float* __restrict__ rnorm_ws,
                                          const unsigned short* __restrict__ attn_g,
                                          const float* __restrict__ asum_p,
                                          float* __restrict__ vlad,
                                          float* __restrict__ ssqnk_p) {
    const int b = blockIdx.x, t = threadIdx.x;
    const int n = b >> 5, ct = b & 31;
    const int lane = t & 63, wvi = t >> 6;
    const int quad = lane >> 4, l15 = lane & 15;
    const int mt = wvi & 1, nt = wvi >> 1;
    const int krow = mt * 16 + l15;
    const int crow = ct * 32 + nt * 16 + l15;
    if (t < 32) {
        float s = 0.f;
        #pragma unroll
        for (int ps = 0; ps < 16; ++ps) s += asum_p[(n * 16 + ps) * KK + t];
        sm.asum[t] = s;
        sm.ssq[t] = 0.f;
    }
    __syncthreads();
    const unsigned short* apq = attn_g + ((size_t)n * KK + krow) * PP + quad * 8;
    const T* xp = x + (size_t)n * CC * PP + (size_t)crow * PP + quad * 8;
    const float* rp = rnorm_ws + n * PP + quad * 8;
    f32x4 acc = {0.f, 0.f, 0.f, 0.f};
    // depth-4 register pipeline over 32 p-steps (full unroll -> static slots)
    bf16x8 avq[4]; f32x4 xq0[4], xq1[4], rq0[4], rq1[4];
    #pragma unroll
    for (int ii = 0; ii < 4; ++ii) {
        const int o = ii * 32;
        avq[ii] = *(const bf16x8*)&apq[o];
        xq0[ii] = IO<T>::ld4(&xp[o]); xq1[ii] = IO<T>::ld4(&xp[o + 4]);
        rq0[ii] = *(const f32x4*)&rp[o]; rq1[ii] = *(const f32x4*)&rp[o + 4];
    }
    #pragma unroll
    for (int st = 0; st < 32; ++st) {
        const int sl = st & 3;
        bf16x8 bv;
        #pragma unroll
        for (int jj = 0; jj < 4; ++jj) {
            bv[jj]     = (short)f2bf(xq0[sl][jj] * rq0[sl][jj]);
            bv[4 + jj] = (short)f2bf(xq1[sl][jj] * rq1[sl][jj]);
        }
        acc = __builtin_amdgcn_mfma_f32_16x16x32_bf16(avq[sl], bv, acc, 0, 0, 0);
        if (st + 4 < 32) {
            const int o = (st + 4) * 32;
            avq[sl] = *(const bf16x8*)&apq[o];
            xq0[sl] = IO<T>::ld4(&xp[o]); xq1[sl] = IO<T>::ld4(&xp[o + 4]);
            rq0[sl] = *(const f32x4*)&rp[o]; rq1[sl] = *(const f32x4*)&rp[o + 4];
        }
    }
    #pragma unroll
    for (int reg = 0; reg < 4; ++reg) {
        const int kk = mt * 16 + quad * 4 + reg;
        const float A = sm.asum[kk];
        const float v = acc[reg] - A * IO<T>::ld(&cent[kk * CC + crow]);
        vlad[((size_t)n * KK + kk) * CC + crow] = v;
        float sq = v * v;
        sq += __shfl_xor(sq, 1, 64);
        sq += __shfl_xor(sq, 2, 64);
        sq += __shfl_xor(sq, 4, 64);
        sq += __shfl_xor(sq, 8, 64);
        if (l15 == 0) atomicAdd(&sm.ssq[kk], sq);
    }
    __syncthreads();
    if (t < 32) ssqnk_p[(n * 32 + ct) * KK + t] = sm.ssq[t];
}

__global__ __launch_bounds__(256) void k_vlad(const void* __restrict__ xv,
                                              const void* __restrict__ centv,
                                              const int* __restrict__ flag,
                                              const float* __restrict__ rnorm_ws,
                                              const unsigned short* __restrict__ attn_g,
                                              const float* __restrict__ asum_p,
                                              float* __restrict__ vlad,
                                              float* __restrict__ ssqnk_p) {
    __shared__ VladSmem sm;
    if (*flag) vlad_body<float>((const float*)xv, (const float*)centv, sm, rnorm_ws,
                                attn_g, asum_p, vlad, ssqnk_p);
    else       vlad_body<unsigned short>((const unsigned short*)xv, (const unsigned short*)centv,
                                         sm, rnorm_ws, attn_g, asum_p, vlad, ssqnk_p);
}

// ---------------------------------------------------------------------------
// K3: factors + scaled output. grid 512 = (n, k), block 256. (R5-verified.)
// ---------------------------------------------------------------------------
struct OutSmem { float ssq[32]; float rint[32]; float rg; };

template <typename T>
__device__ __forceinline__ void out_body(const float* __restrict__ vlad,
                                         const float* __restrict__ ssqnk_p,
                                         OutSmem& sm, T* __restrict__ out) {
    const int b = blockIdx.x, t = threadIdx.x;
    const int n = b >> 5, k = b & 31;
    if (t < 32) {
        float s = 0.f;
        #pragma unroll
        for (int ct = 0; ct < 32; ++ct) s += ssqnk_p[(n * 32 + ct) * KK + t];
        sm.ssq[t] = s;
    }
    __syncthreads();
    if (t < 64) {
        const float s = (t < 32) ? sm.ssq[t] : 0.f;
        const float rr = 1.0f / fmaxf(sqrtf(s), EPSF);
        float gg = s * rr * rr;
        #pragma unroll
        for (int off = 32; off > 0; off >>= 1) gg += __shfl_down(gg, off, 64);
        if (t == 0) sm.rg = 1.0f / fmaxf(sqrtf(gg), EPSF);
        if (t < 32) sm.rint[t] = rr;
    }
    __syncthreads();
    const float f = sm.rint[k] * sm.rg;
    const size_t ob = ((size_t)n * KK + k) * CC + 4 * t;
    f32x4 v = *(const f32x4*)&vlad[ob];
    v[0] *= f; v[1] *= f; v[2] *= f; v[3] *= f;
    IO<T>::st4(&out[ob], v);
}

__global__ __launch_bounds__(256) void k_out(const float* __restrict__ vlad,
                                             const float* __restrict__ ssqnk_p,
                                             const int* __restrict__ flag,
                                             void* __restrict__ outv) {
    __shared__ OutSmem sm;
    if (*flag) out_body<float>(vlad, ssqnk_p, sm, (float*)outv);
    else       out_body<unsigned short>(vlad, ssqnk_p, sm, (unsigned short*)outv);
}

extern "C" void kernel_launch(void* const* d_in, const int* in_sizes, int n_in,
                              void* d_out, int out_size, void* d_ws, size_t ws_size,
                              hipStream_t stream) {
    const void* x    = d_in[0];
    const void* w    = d_in[1];
    const void* cent = d_in[2];

    float* ws       = (float*)d_ws;
    float* rnorm_ws = ws;                                   // NB*PP = 16384 fl
    float* asum_p   = rnorm_ws + NB * PP;                   // NB*16*KK = 8192 fl
    float* ssqnk_p  = asum_p + NB * 16 * KK;                // NB*32*KK = 16384 fl
    float* vlad     = ssqnk_p + NB * 32 * KK;               // NB*KK*CC = 524288 fl
    int*   flag     = (int*)(vlad + (size_t)NB * KK * CC);  // 4 ints
    unsigned short* attn_g = (unsigned short*)(flag + 4);   // NB*KK*PP sh (1MB)

    k_attn<<<NB * 16, 256, 0, stream>>>(x, w, flag, rnorm_ws, attn_g, asum_p);
    k_vlad<<<NB * 32, 256, 0, stream>>>(x, cent, flag, rnorm_ws, attn_g, asum_p,
                                        vlad, ssqnk_p);
    k_out<<<NB * KK, 256, 0, stream>>>(vlad, ssqnk_p, flag, d_out);
}

// Round 9
// 130.029 us; speedup vs baseline: 1.0799x; 1.0226x over previous
//
#include <hip/hip_runtime.h>

// NetVLAD: N=16, C=1024, P=1024, K=32. Three dispatches.
//  k_attn: fused logits+rnorm+softmax. grid 512 = (n, 32-p tile) -> 2 blk/CU,
//     block 256 = 4 waves (wv>>1 = k-half, wv&1 = p-half). 8 chunks of 128 c:
//     fp32 x loads (256B segments), 4x4 register transpose -> dbuf LDS,
//     depth-1 prefetch, lgkmcnt-only barrier (loads in flight). Epilogue in
//     a UNION over the staging LDS: parallel softmax (8 thr/px), stores
//     a' = a * rnorm (bf16) -> vlad needs NO rnorm, asum = sum(a) in fp32.
//  k_vlad: (n, 32c-tile) fragment-direct MFMA from global: a' (L2-hot) x raw
//     x (2 loads/step/lane, was 4). Fused -asum*cent, ssq partials.
//  k_out: (n, k) intra+global norms, scaled write. (Verified, unchanged.)
// Runtime dtype detect (fp32 vs bf16) per block; fp32 accumulate throughout.
#define NB   16
#define CC   1024
#define PP   1024
#define KK   32
#define EPSF 1e-12f

typedef __attribute__((ext_vector_type(8))) short  bf16x8;
typedef __attribute__((ext_vector_type(4))) float  f32x4;

__device__ __forceinline__ float bf2f(unsigned short u) {
    union { unsigned int i; float f; } v; v.i = ((unsigned int)u) << 16; return v.f;
}
__device__ __forceinline__ unsigned short f2bf(float f) {
    union { float f; unsigned int i; } v; v.f = f;
    return (unsigned short)((v.i + 0x7fffu + ((v.i >> 16) & 1u)) >> 16);  // RNE
}

template <typename T> struct IO;
template <> struct IO<float> {
    static __device__ __forceinline__ float ld(const float* p) { return *p; }
    static __device__ __forceinline__ f32x4 ld4(const float* p) { return *(const f32x4*)p; }
    static __device__ __forceinline__ void st4(float* p, f32x4 v) { *(f32x4*)p = v; }
};
template <> struct IO<unsigned short> {
    static __device__ __forceinline__ float ld(const unsigned short* p) { return bf2f(*p); }
    static __device__ __forceinline__ f32x4 ld4(const unsigned short* p) {
        const ushort4 u = *(const ushort4*)p;
        f32x4 r; r[0] = bf2f(u.x); r[1] = bf2f(u.y); r[2] = bf2f(u.z); r[3] = bf2f(u.w);
        return r;
    }
    static __device__ __forceinline__ void st4(unsigned short* p, f32x4 v) {
        ushort4 u;
        u.x = f2bf(v[0]); u.y = f2bf(v[1]); u.z = f2bf(v[2]); u.w = f2bf(v[3]);
        *(ushort4*)p = u;
    }
};

// Barrier WITHOUT vmcnt drain: waves wait only their own LDS ops; prefetch
// global loads stay in flight across the barrier.
__device__ __forceinline__ void wg_sync_fast() {
    asm volatile("s_waitcnt lgkmcnt(0)" ::: "memory");
    __builtin_amdgcn_s_barrier();
    asm volatile("" ::: "memory");
}

// ---------------------------------------------------------------------------
// K1: fused attn. grid 512 = (n<<5 | ptile), block 256.
// ---------------------------------------------------------------------------
struct __align__(16) AttnSmem {
    union {
        struct {                            // main loop (~34.8 KB)
            unsigned short xT[2][32][136];  // [buf][p][c] 272B rows
            unsigned short Wl[2][32][136];  // [buf][k][c]
        } m;
        struct {                            // epilogue (~11 KB)
            float red[32][32];              // sumsq [c-quad][p]
            float lg[32][33];               // logits [p][k]
            float rn[32];
            float asq[4][32];               // per-wave asum partials [wv][k]
            unsigned short at[32][33];      // a' bf16 [k][p]
        } e;
    } u;
};

template <typename T>
__device__ __forceinline__ void attn_body(const T* __restrict__ x,
                                          const T* __restrict__ w,
                                          AttnSmem& sm,
                                          unsigned short* __restrict__ attn_g,
                                          float* __restrict__ asum_p) {
    const int b = blockIdx.x, t = threadIdx.x;
    const int n = b >> 5, pt = b & 31, p0 = pt * 32;
    const int lane = t & 63, wv = t >> 6;
    const int quad = lane >> 4, l15 = lane & 15;
    const int khalf = wv >> 1, phalf = wv & 1;
    const int ci = t >> 3;          // c-quad 0..31 (rows 4ci..4ci+3 of chunk)
    const int pj = t & 7;           // p-quad (p 4pj..4pj+3)
    const int wk = t >> 3;          // W staging k-row 0..31
    const int wc = (t & 7) * 16;    // W staging c-offset (16 c)
    const size_t xb = (size_t)n * CC * PP + p0;

    float ss[4] = {0.f, 0.f, 0.f, 0.f};
    f32x4 acc = {0.f, 0.f, 0.f, 0.f};

    // depth-1 prefetch registers
    f32x4 xr[4], wr[4];
    #pragma unroll
    for (int r = 0; r < 4; ++r) {
        xr[r] = IO<T>::ld4(&x[xb + (size_t)(4 * ci + r) * PP + 4 * pj]);
        wr[r] = IO<T>::ld4(&w[wk * CC + wc + 4 * r]);
    }

    #pragma unroll
    for (int ch = 0; ch < 8; ++ch) {
        const int buf = ch & 1;
        // 4x4 register transpose -> xT, sumsq
        #pragma unroll
        for (int jj = 0; jj < 4; ++jj) {
            ss[jj] += xr[0][jj] * xr[0][jj] + xr[1][jj] * xr[1][jj]
                    + xr[2][jj] * xr[2][jj] + xr[3][jj] * xr[3][jj];
            ushort4 u;
            u.x = f2bf(xr[0][jj]); u.y = f2bf(xr[1][jj]);
            u.z = f2bf(xr[2][jj]); u.w = f2bf(xr[3][jj]);
            *(ushort4*)&sm.u.m.xT[buf][4 * pj + jj][4 * ci] = u;
        }
        // W chunk -> Wl
        #pragma unroll
        for (int r = 0; r < 4; ++r) {
            ushort4 u;
            u.x = f2bf(wr[r][0]); u.y = f2bf(wr[r][1]);
            u.z = f2bf(wr[r][2]); u.w = f2bf(wr[r][3]);
            *(ushort4*)&sm.u.m.Wl[buf][wk][wc + 4 * r] = u;
        }
        // issue next-chunk loads; they stay in flight across the barrier
        if (ch < 7) {
            const int c0 = (ch + 1) * 128;
            #pragma unroll
            for (int r = 0; r < 4; ++r) {
                xr[r] = IO<T>::ld4(&x[xb + (size_t)(c0 + 4 * ci + r) * PP + 4 * pj]);
                wr[r] = IO<T>::ld4(&w[wk * CC + c0 + wc + 4 * r]);
            }
        }
        wg_sync_fast();
        // MFMA: A = W k-rows, B = xT p-rows; D row m -> k = khalf*16+quad*4+reg,
        // col n -> p = phalf*16 + l15. (Layout verified by R8 pass.)
        #pragma unroll
        for (int ks = 0; ks < 4; ++ks) {
            const bf16x8 av = *(const bf16x8*)&sm.u.m.Wl[buf][khalf * 16 + l15][ks * 32 + quad * 8];
            const bf16x8 bv = *(const bf16x8*)&sm.u.m.xT[buf][phalf * 16 + l15][ks * 32 + quad * 8];
            acc = __builtin_amdgcn_mfma_f32_16x16x32_bf16(av, bv, acc, 0, 0, 0);
        }
    }
    __syncthreads();   // main-loop LDS dead beyond here; union reuse is safe

    // sumsq partials + logits into epilogue arrays
    #pragma unroll
    for (int jj = 0; jj < 4; ++jj) sm.u.e.red[ci][4 * pj + jj] = ss[jj];
    #pragma unroll
    for (int reg = 0; reg < 4; ++reg)
        sm.u.e.lg[phalf * 16 + l15][khalf * 16 + quad * 4 + reg] = acc[reg];
    __syncthreads();
    if (t < 32) {
        float s = 0.f;
        #pragma unroll
        for (int g = 0; g < 32; ++g) s += sm.u.e.red[g][t];
        sm.u.e.rn[t] = 1.0f / fmaxf(sqrtf(s), EPSF);
    }
    __syncthreads();
    {   // parallel softmax: p = t>>3, 4 k per thread, 8-lane k-reduction
        const int p = t >> 3, kg = (t & 7) * 4;
        const float rr = sm.u.e.rn[p];
        float l[4];
        #pragma unroll
        for (int q = 0; q < 4; ++q) l[q] = sm.u.e.lg[p][kg + q] * rr;
        float mx = fmaxf(fmaxf(l[0], l[1]), fmaxf(l[2], l[3]));
        mx = fmaxf(mx, __shfl_xor(mx, 1, 64));
        mx = fmaxf(mx, __shfl_xor(mx, 2, 64));
        mx = fmaxf(mx, __shfl_xor(mx, 4, 64));
        float e[4], sum = 0.f;
        #pragma unroll
        for (int q = 0; q < 4; ++q) { e[q] = expf(l[q] - mx); sum += e[q]; }
        sum += __shfl_xor(sum, 1, 64);
        sum += __shfl_xor(sum, 2, 64);
        sum += __shfl_xor(sum, 4, 64);
        const float inv = 1.0f / sum;
        float a[4];
        #pragma unroll
        for (int q = 0; q < 4; ++q) {
            a[q] = e[q] * inv;                       // fp32 a (for asum)
            sm.u.e.at[kg + q][p] = f2bf(a[q] * rr);  // a' = a * rnorm (bf16)
        }
        // asum partial: reduce over the wave's 8 p (lane bits 3..5)
        #pragma unroll
        for (int q = 0; q < 4; ++q) {
            a[q] += __shfl_xor(a[q], 8, 64);
            a[q] += __shfl_xor(a[q], 16, 64);
            a[q] += __shfl_xor(a[q], 32, 64);
        }
        if ((lane >> 3) == 0) {
            #pragma unroll
            for (int q = 0; q < 4; ++q) sm.u.e.asq[wv][kg + q] = a[q];
        }
    }
    __syncthreads();
    if (t < 32)
        asum_p[(n * 32 + pt) * KK + t]
            = sm.u.e.asq[0][t] + sm.u.e.asq[1][t] + sm.u.e.asq[2][t] + sm.u.e.asq[3][t];
    {   // coalesced a' write: k = t>>3, 4 p per thread (8 B)
        const int k = t >> 3, po = (t & 7) * 4;
        ushort4 u;
        u.x = sm.u.e.at[k][po];     u.y = sm.u.e.at[k][po + 1];
        u.z = sm.u.e.at[k][po + 2]; u.w = sm.u.e.at[k][po + 3];
        *(ushort4*)&attn_g[((size_t)n * KK + k) * PP + p0 + po] = u;
    }
}

__global__ __launch_bounds__(256) void k_attn(const void* __restrict__ xv,
                                              const void* __restrict__ wv,
                                              int* __restrict__ flag,
                                              unsigned short* __restrict__ attn_g,
                                              float* __restrict__ asum_p) {
    __shared__ AttnSmem sm;
    __shared__ int s_bad;
    const int t = threadIdx.x;
    if (t == 0) s_bad = 0;
    __syncthreads();
    {   // per-block dtype detect (8KB prefix, L2-broadcast across blocks)
        const unsigned short* xu = (const unsigned short*)xv;
        int bad = 0;
        for (int ii = t; ii < 4096; ii += 256)
            if (((xu[ii] >> 7) & 0xFFu) > 0x9Fu) bad = 1;
        if (bad) atomicOr(&s_bad, 1);
    }
    __syncthreads();
    const int f = s_bad;
    if (blockIdx.x == 0 && t == 0) flag[0] = f;   // for later kernels
    if (f) attn_body<float>((const float*)xv, (const float*)wv, sm, attn_g, asum_p);
    else   attn_body<unsigned short>((const unsigned short*)xv, (const unsigned short*)wv,
                                     sm, attn_g, asum_p);
}

// ---------------------------------------------------------------------------
// K2: vlad GEMM, fragment-direct from global. a' carries rnorm -> raw x loads
// only (2 loads/step/lane, was 4; no per-element multiply).
// grid 512 = (n, 32c-tile), block 256.
// ---------------------------------------------------------------------------
struct VladSmem { float asum[32]; float ssq[32]; };

template <typename T>
__device__ __forceinline__ void vlad_body(const T* __restrict__ x,
                                          const T* __restrict__ cent, VladSmem& sm,
                                          const unsigned short* __restrict__ attn_g,
                                          const float* __restrict__ asum_p,
                                          float* __restrict__ vlad,
                                          float* __restrict__ ssqnk_p) {
    const int b = blockIdx.x, t = threadIdx.x;
    const int n = b >> 5, ct = b & 31;
    const int lane = t & 63, wvi = t >> 6;
    const int quad = lane >> 4, l15 = lane & 15;
    const int mt = wvi & 1, nt = wvi >> 1;
    const int krow = mt * 16 + l15;
    const int crow = ct * 32 + nt * 16 + l15;
    if (t < 32) {
        float s = 0.f;
        #pragma unroll
        for (int ps = 0; ps < 32; ++ps) s += asum_p[(n * 32 + ps) * KK + t];
        sm.asum[t] = s;
        sm.ssq[t] = 0.f;
    }
    __syncthreads();
    const unsigned short* apq = attn_g + ((size_t)n * KK + krow) * PP + quad * 8;
    const T* xp = x + (size_t)n * CC * PP + (size_t)crow * PP + quad * 8;
    f32x4 acc = {0.f, 0.f, 0.f, 0.f};
    // depth-4 register pipeline over 32 p-steps (full unroll -> static slots)
    bf16x8 avq[4]; f32x4 xq0[4], xq1[4];
    #pragma unroll
    for (int ii = 0; ii < 4; ++ii) {
        const int o = ii * 32;
        avq[ii] = *(const bf16x8*)&apq[o];
        xq0[ii] = IO<T>::ld4(&xp[o]); xq1[ii] = IO<T>::ld4(&xp[o + 4]);
    }
    #pragma unroll
    for (int st = 0; st < 32; ++st) {
        const int sl = st & 3;
        bf16x8 bv;
        #pragma unroll
        for (int jj = 0; jj < 4; ++jj) {
            bv[jj]     = (short)f2bf(xq0[sl][jj]);
            bv[4 + jj] = (short)f2bf(xq1[sl][jj]);
        }
        acc = __builtin_amdgcn_mfma_f32_16x16x32_bf16(avq[sl], bv, acc, 0, 0, 0);
        if (st + 4 < 32) {
            const int o = (st + 4) * 32;
            avq[sl] = *(const bf16x8*)&apq[o];
            xq0[sl] = IO<T>::ld4(&xp[o]); xq1[sl] = IO<T>::ld4(&xp[o + 4]);
        }
    }
    #pragma unroll
    for (int reg = 0; reg < 4; ++reg) {
        const int kk = mt * 16 + quad * 4 + reg;
        const float A = sm.asum[kk];
        const float v = acc[reg] - A * IO<T>::ld(&cent[kk * CC + crow]);
        vlad[((size_t)n * KK + kk) * CC + crow] = v;
        float sq = v * v;
        sq += __shfl_xor(sq, 1, 64);
        sq += __shfl_xor(sq, 2, 64);
        sq += __shfl_xor(sq, 4, 64);
        sq += __shfl_xor(sq, 8, 64);
        if (l15 == 0) atomicAdd(&sm.ssq[kk], sq);
    }
    __syncthreads();
    if (t < 32) ssqnk_p[(n * 32 + ct) * KK + t] = sm.ssq[t];
}

__global__ __launch_bounds__(256) void k_vlad(const void* __restrict__ xv,
                                              const void* __restrict__ centv,
                                              const int* __restrict__ flag,
                                              const unsigned short* __restrict__ attn_g,
                                              const float* __restrict__ asum_p,
                                              float* __restrict__ vlad,
                                              float* __restrict__ ssqnk_p) {
    __shared__ VladSmem sm;
    if (*flag) vlad_body<float>((const float*)xv, (const float*)centv, sm,
                                attn_g, asum_p, vlad, ssqnk_p);
    else       vlad_body<unsigned short>((const unsigned short*)xv, (const unsigned short*)centv,
                                         sm, attn_g, asum_p, vlad, ssqnk_p);
}

// ---------------------------------------------------------------------------
// K3: factors + scaled output. grid 512 = (n, k), block 256. (Verified.)
// ---------------------------------------------------------------------------
struct OutSmem { float ssq[32]; float rint[32]; float rg; };

template <typename T>
__device__ __forceinline__ void out_body(const float* __restrict__ vlad,
                                         const float* __restrict__ ssqnk_p,
                                         OutSmem& sm, T* __restrict__ out) {
    const int b = blockIdx.x, t = threadIdx.x;
    const int n = b >> 5, k = b & 31;
    if (t < 32) {
        float s = 0.f;
        #pragma unroll
        for (int ct = 0; ct < 32; ++ct) s += ssqnk_p[(n * 32 + ct) * KK + t];
        sm.ssq[t] = s;
    }
    __syncthreads();
    if (t < 64) {
        const float s = (t < 32) ? sm.ssq[t] : 0.f;
        const float rr = 1.0f / fmaxf(sqrtf(s), EPSF);
        float gg = s * rr * rr;
        #pragma unroll
        for (int off = 32; off > 0; off >>= 1) gg += __shfl_down(gg, off, 64);
        if (t == 0) sm.rg = 1.0f / fmaxf(sqrtf(gg), EPSF);
        if (t < 32) sm.rint[t] = rr;
    }
    __syncthreads();
    const float f = sm.rint[k] * sm.rg;
    const size_t ob = ((size_t)n * KK + k) * CC + 4 * t;
    f32x4 v = *(const f32x4*)&vlad[ob];
    v[0] *= f; v[1] *= f; v[2] *= f; v[3] *= f;
    IO<T>::st4(&out[ob], v);
}

__global__ __launch_bounds__(256) void k_out(const float* __restrict__ vlad,
                                             const float* __restrict__ ssqnk_p,
                                             const int* __restrict__ flag,
                                             void* __restrict__ outv) {
    __shared__ OutSmem sm;
    if (*flag) out_body<float>(vlad, ssqnk_p, sm, (float*)outv);
    else       out_body<unsigned short>(vlad, ssqnk_p, sm, (unsigned short*)outv);
}

extern "C" void kernel_launch(void* const* d_in, const int* in_sizes, int n_in,
                              void* d_out, int out_size, void* d_ws, size_t ws_size,
                              hipStream_t stream) {
    const void* x    = d_in[0];
    const void* w    = d_in[1];
    const void* cent = d_in[2];

    float* ws      = (float*)d_ws;
    float* asum_p  = ws;                                    // NB*32*KK = 16384 fl
    float* ssqnk_p = asum_p + NB * 32 * KK;                 // NB*32*KK = 16384 fl
    float* vlad    = ssqnk_p + NB * 32 * KK;                // NB*KK*CC = 524288 fl
    int*   flag    = (int*)(vlad + (size_t)NB * KK * CC);   // 4 ints
    unsigned short* attn_g = (unsigned short*)(flag + 4);   // NB*KK*PP sh (1MB)

    k_attn<<<NB * 32, 256, 0, stream>>>(x, w, flag, attn_g, asum_p);
    k_vlad<<<NB * 32, 256, 0, stream>>>(x, cent, flag, attn_g, asum_p, vlad, ssqnk_p);
    k_out<<<NB * KK, 256, 0, stream>>>(vlad, ssqnk_p, flag, d_out);
}